// Round 11
// baseline (274.540 us; speedup 1.0000x reference)
//
#include <hip/hip_runtime.h>
#include <hip/hip_bf16.h>

// MHA: B=4 L=2048 D=1024 H=16 DH=64, causal. Inputs f32 (sniffed; dtype-proof).
// Round 18:
//  - attn reverted to R14-exact (setprio REMOVED: R17 A/B showed -4.5us, the
//    4-wave barrier-synced structure is m190's null regime, not m191's).
//  - GEMMs: BM=256 x BN=128 tiles, 512 threads (8 waves = 4x2 of 64x64 each).
//    Operand-panel L3 traffic scales as (1/BM+1/BN): qkv 786->590MB. Per-wave
//    structure (acc[4][4], swizzles, epilogues) unchanged -- parameter lane.
// attn core: in-register P on 16x16x32, no P-LDS, dbuf + prefetch + 1
// barrier/tile, exp2 domain, defer-max THR=8, MFMA-ones o_sum, position-
// permuted V^T from qkv epilogue, running staging pointers.

typedef __bf16 bf16;
typedef __bf16 bf16x4 __attribute__((ext_vector_type(4)));
typedef __bf16 bf16x8 __attribute__((ext_vector_type(8)));
typedef float f32x4 __attribute__((ext_vector_type(4)));

#define DEV static __device__ __forceinline__

constexpr int B = 4, L = 2048, D = 1024, H = 16, DH = 64;
constexpr int BL = B * L;                      // 8192
constexpr int GM = 8192, GK = 1024;
constexpr int BKg = 64;                        // GEMM K-tile

typedef __attribute__((address_space(1))) const void* gptr1;
typedef __attribute__((address_space(3))) void* lptr3;

DEV void load_lds16(const bf16* g, bf16* l) {
  __builtin_amdgcn_global_load_lds((gptr1)g, (lptr3)l, 16, 0, 0);
}

DEV f32x4 mfma(bf16x8 a, bf16x8 b, f32x4 c) {
  return __builtin_amdgcn_mfma_f32_16x16x32_bf16(a, b, c, 0, 0, 0);
}

DEV float scrub(float v) { return (v == v) ? v : 0.f; }
DEV float max3f(float a, float b, float c) { return fmaxf(fmaxf(a, b), c); }

// ---------- dtype sniff (flag=1: bf16 storage, 0: f32) ----------
__global__ void sniff_k(const unsigned short* __restrict__ xr, int* flag) {
  __shared__ int cnt;
  if (threadIdx.x == 0) cnt = 0;
  __syncthreads();
  int local = 0;
  for (int i = threadIdx.x; i < 4096; i += 256) {
    const unsigned short u = xr[2 * i];
    const int e = (u >> 7) & 0xFF;
    if (e >= 0x70 && e <= 0x85) local++;
  }
  atomicAdd(&cnt, local);
  __syncthreads();
  if (threadIdx.x == 0) *flag = (cnt > 2048) ? 1 : 0;
}

// ---------- merged prep: z=0..3 weight transpose, z=4 x canonicalize ----------
__global__ __launch_bounds__(256) void prep_k(const void* __restrict__ W0,
                                              const void* __restrict__ W1,
                                              const void* __restrict__ W2,
                                              const void* __restrict__ W3,
                                              bf16* __restrict__ dstBase,
                                              const void* __restrict__ x,
                                              bf16* __restrict__ xc,
                                              const int* __restrict__ flag, int n) {
  __shared__ bf16 t[32][33];
  const bool isbf = (*flag != 0);
  const int z = blockIdx.z;
  if (z < 4) {
    const void* src = (z == 0) ? W0 : (z == 1) ? W1 : (z == 2) ? W2 : W3;
    bf16* dst = dstBase + (size_t)z * D * D;
    const int bx = blockIdx.x * 32, by = blockIdx.y * 32;
    const int tx = threadIdx.x & 31, ty = threadIdx.x >> 5;
    for (int i = ty; i < 32; i += 8) {
      const size_t off = (size_t)(by + i) * D + bx + tx;
      const float v = isbf ? (float)((const bf16*)src)[off] : ((const float*)src)[off];
      t[i][tx] = (bf16)scrub(v);
    }
    __syncthreads();
    for (int i = ty; i < 32; i += 8)
      dst[(size_t)(bx + i) * D + by + tx] = t[tx][i];
  } else {
    const int bid = blockIdx.y * 32 + blockIdx.x;       // 0..1023
    const int stride = 1024 * 256 * 8;
    for (int idx = (bid * 256 + (int)threadIdx.x) * 8; idx < n; idx += stride) {
      bf16x8 o;
      if (isbf) {
        bf16x8 v = *(const bf16x8*)((const bf16*)x + idx);
        #pragma unroll
        for (int j = 0; j < 8; ++j) o[j] = (bf16)scrub((float)v[j]);
      } else {
        const float* s = (const float*)x + idx;
        #pragma unroll
        for (int j = 0; j < 8; ++j) o[j] = (bf16)scrub(s[j]);
      }
      *(bf16x8*)&xc[idx] = o;
    }
  }
}

// ---------- fused QKV GEMM: [Q|K|V] = x @ [WqT|WkT|WvT]^T + b ----------
// 256x128 tile, 512 threads, 8 waves (4 m-rows x 2 n-cols of 64x64 each).
// Q epilogue folds 0.125*log2(e); V epilogue writes VT[bh][d][pos] directly
// (position permutation pos = 4*hi16 + 8*q4 + r within each 32-key group).
__global__ __launch_bounds__(512) void qkv_gemm_k(const bf16* __restrict__ A,
                                                  const bf16* __restrict__ Bt,
                                                  const void* __restrict__ bq,
                                                  const void* __restrict__ bk,
                                                  const void* __restrict__ bv,
                                                  bf16* __restrict__ Q,
                                                  bf16* __restrict__ Kk,
                                                  bf16* __restrict__ VT,
                                                  const int* __restrict__ flag) {
  __shared__ __align__(16) bf16 As[256 * BKg];
  __shared__ __align__(16) bf16 Bs[128 * BKg];
  const bool isbf = (*flag != 0);
  const int m0 = blockIdx.x * 256, n0 = blockIdx.y * 128;
  const int buf = n0 >> 10, nloc = n0 & 1023;
  const void* bias = (buf == 0) ? bq : (buf == 1) ? bk : bv;
  const float scale = (buf == 0) ? 0.18033688011111f : 1.0f; // 0.125*log2(e)

  const int tid = threadIdx.x, wave = tid >> 6, lane = tid & 63;
  const int wr = wave >> 1, wc = wave & 1;   // 4 m-rows x 2 n-cols
  const int quad = lane >> 4, l16 = lane & 15;
  const int srow = lane >> 3;
  const int scol = ((lane ^ srow) & 7) * 8;
  const int l7 = l16 & 7;
  const int s0 = ((quad ^ l7) * 8);
  const int s1 = s0 ^ 32;

  f32x4 acc[4][4] = {};

  for (int k0 = 0; k0 < GK; k0 += BKg) {
    for (int c = wave; c < 32; c += 8)
      load_lds16(A  + (size_t)(m0 + c * 8 + srow) * GK + k0 + scol, &As[c * 512]);
    for (int c = wave; c < 16; c += 8)
      load_lds16(Bt + (size_t)(n0 + c * 8 + srow) * GK + k0 + scol, &Bs[c * 512]);
    __syncthreads();
    #pragma unroll
    for (int kk = 0; kk < BKg; kk += 32) {
      const int sk = kk ? s1 : s0;
      bf16x8 af[4], bfr[4];
      #pragma unroll
      for (int i = 0; i < 4; ++i)
        af[i] = *(const bf16x8*)&As[(wr * 64 + i * 16 + l16) * BKg + sk];
      #pragma unroll
      for (int i = 0; i < 4; ++i)
        bfr[i] = *(const bf16x8*)&Bs[(wc * 64 + i * 16 + l16) * BKg + sk];
      #pragma unroll
      for (int mi = 0; mi < 4; ++mi)
        #pragma unroll
        for (int ni = 0; ni < 4; ++ni)
          acc[mi][ni] = mfma(af[mi], bfr[ni], acc[mi][ni]);
    }
    __syncthreads();
  }

  if (buf < 2) {
    bf16* Cb = (buf == 0) ? Q : Kk;
    #pragma unroll
    for (int ni = 0; ni < 4; ++ni) {
      const int col = nloc + wc * 64 + ni * 16 + l16;
      const float bv2 = isbf ? (float)((const bf16*)bias)[col] : ((const float*)bias)[col];
      #pragma unroll
      for (int mi = 0; mi < 4; ++mi)
        #pragma unroll
        for (int r = 0; r < 4; ++r) {
          const int row = m0 + wr * 64 + mi * 16 + quad * 4 + r;
          Cb[(size_t)row * D + col] = (bf16)((acc[mi][ni][r] + bv2) * scale);
        }
    }
  } else {
    // V -> VT[bh][d][pos], position-permuted, bf16x4 per acc column
    #pragma unroll
    for (int ni = 0; ni < 4; ++ni) {
      const int col = nloc + wc * 64 + ni * 16 + l16;   // feature c in [0,1024)
      const int h = col >> 6, d = col & 63;
      const float bv2 = isbf ? (float)((const bf16*)bias)[col] : ((const float*)bias)[col];
      #pragma unroll
      for (int mi = 0; mi < 4; ++mi) {
        const int row = m0 + wr * 64 + mi * 16 + quad * 4;  // token base, 4-aligned
        const int bb = row >> 11, l = row & 2047;
        const int pos = (l & ~31) + 4 * ((l >> 4) & 1) + 8 * ((l >> 2) & 3);
        bf16x4 pk;
        #pragma unroll
        for (int r = 0; r < 4; ++r) pk[r] = (bf16)(acc[mi][ni][r] + bv2);
        *(bf16x4*)&VT[((size_t)(bb * 16 + h) * 64 + d) * L + pos] = pk;
      }
    }
  }
}

// ---------- final GEMM: out = attnO @ WoT^T + bo (dtype per flag) ----------
// 256x128 tile, 512 threads, 8 waves (4x2 of 64x64).
__global__ __launch_bounds__(512) void gemm_bt_k(const bf16* __restrict__ A,
                                                 const bf16* __restrict__ Bt,
                                                 const void* __restrict__ bias,
                                                 void* __restrict__ C,
                                                 const int* __restrict__ flag) {
  __shared__ __align__(16) bf16 As[256 * BKg];
  __shared__ __align__(16) bf16 Bs[128 * BKg];
  const bool isbf = (*flag != 0);
  const int m0 = blockIdx.x * 256, n0 = blockIdx.y * 128;
  const int tid = threadIdx.x, wave = tid >> 6, lane = tid & 63;
  const int wr = wave >> 1, wc = wave & 1;
  const int quad = lane >> 4, l16 = lane & 15;
  const int srow = lane >> 3;
  const int scol = ((lane ^ srow) & 7) * 8;
  const int l7 = l16 & 7;
  const int s0 = ((quad ^ l7) * 8);
  const int s1 = s0 ^ 32;

  f32x4 acc[4][4] = {};

  for (int k0 = 0; k0 < GK; k0 += BKg) {
    for (int c = wave; c < 32; c += 8)
      load_lds16(A  + (size_t)(m0 + c * 8 + srow) * GK + k0 + scol, &As[c * 512]);
    for (int c = wave; c < 16; c += 8)
      load_lds16(Bt + (size_t)(n0 + c * 8 + srow) * GK + k0 + scol, &Bs[c * 512]);
    __syncthreads();
    #pragma unroll
    for (int kk = 0; kk < BKg; kk += 32) {
      const int sk = kk ? s1 : s0;
      bf16x8 af[4], bfr[4];
      #pragma unroll
      for (int i = 0; i < 4; ++i)
        af[i] = *(const bf16x8*)&As[(wr * 64 + i * 16 + l16) * BKg + sk];
      #pragma unroll
      for (int i = 0; i < 4; ++i)
        bfr[i] = *(const bf16x8*)&Bs[(wc * 64 + i * 16 + l16) * BKg + sk];
      #pragma unroll
      for (int mi = 0; mi < 4; ++mi)
        #pragma unroll
        for (int ni = 0; ni < 4; ++ni)
          acc[mi][ni] = mfma(af[mi], bfr[ni], acc[mi][ni]);
    }
    __syncthreads();
  }

  bf16* Cb = (bf16*)C;
  float* Cf = (float*)C;
  #pragma unroll
  for (int ni = 0; ni < 4; ++ni) {
    const int col = n0 + wc * 64 + ni * 16 + l16;
    const float bv = isbf ? (float)((const bf16*)bias)[col] : ((const float*)bias)[col];
    #pragma unroll
    for (int mi = 0; mi < 4; ++mi)
      #pragma unroll
      for (int r = 0; r < 4; ++r) {
        const int row = m0 + wr * 64 + mi * 16 + quad * 4 + r;
        const float v = acc[mi][ni][r] + bv;
        if (isbf) Cb[(size_t)row * D + col] = (bf16)v;
        else      Cf[(size_t)row * D + col] = v;
      }
  }
}

// ---------- fused causal flash attention v8.2 (R14-exact, no setprio) ----------
// QBLK=64: 4 waves x 16 q-rows, 64-key tiles. In-register P on 16x16x32,
// position-permuted V^T, dbuf + prefetch + 1 barrier/tile, exp2 domain,
// defer-max THR=8, MFMA-ones o_sum, running staging pointers.
__global__ __launch_bounds__(256) void attn_k(bf16* QO,
                                              const bf16* __restrict__ K,
                                              const bf16* __restrict__ VT) {
  __shared__ __align__(16) bf16 Ks[2][64 * 64];    // swizzled [key][d], dbuf
  __shared__ __align__(16) bf16 Vt[2][64 * 64];    // swizzled [d][pos], dbuf

  const int bx = blockIdx.x;
  const int qt = (L / 64 - 1) - (bx >> 6);         // longest blocks first
  const int bh = bx & 63;
  const int b = bh >> 4, h = bh & 15;
  const int tid = threadIdx.x, wave = tid >> 6, lane = tid & 63;
  const int quad = lane >> 4, l16 = lane & 15;
  const int srow = lane >> 3;
  const int scol = ((lane ^ srow) & 7) * 8;
  const int l7 = l16 & 7;
  const int s0 = ((quad ^ l7) * 8);
  const int s1 = s0 ^ 32;

  bf16* Qb = QO + (size_t)b * L * D + h * DH;
  const bf16* Kb = K + (size_t)b * L * D + h * DH;
  const bf16* VTg = VT + (size_t)bh * DH * L;

  // Q B-frags (scale 0.125*log2e pre-folded by QKV GEMM)
  const int qrow = qt * 64 + wave * 16 + l16;
  const bf16x8 qf0 = *(const bf16x8*)(Qb + (size_t)qrow * D + quad * 8);
  const bf16x8 qf1 = *(const bf16x8*)(Qb + (size_t)qrow * D + 32 + quad * 8);

  bf16x8 ones;
  #pragma unroll
  for (int j = 0; j < 8; ++j) ones[j] = (bf16)1.0f;

  float m_run = -INFINITY;                // log2-domain max for q = l16
  f32x4 o_acc[4] = {};                    // C row=quad*4+r -> q, col=l16 -> d
  f32x4 o_sum = {};                       // MFMA row-sum, same layout

  const int nkt = qt + 1;

  // staging pointers (this wave's two chunks), advanced per tile
  const bf16* kg0 = Kb + (size_t)(wave * 8 + srow) * D + scol;
  const bf16* kg1 = kg0 + (size_t)32 * D;
  const bf16* vg0 = VTg + (size_t)(wave * 8 + srow) * L + scol;
  const bf16* vg1 = vg0 + (size_t)32 * L;
  const int kl0 = wave * 512, kl1 = kl0 + 2048;    // LDS chunk offsets

  // prologue: stage tile 0 into buf 0
  load_lds16(kg0, &Ks[0][kl0]);
  load_lds16(kg1, &Ks[0][kl1]);
  load_lds16(vg0, &Vt[0][kl0]);
  load_lds16(vg1, &Vt[0][kl1]);
  kg0 += (size_t)64 * D; kg1 += (size_t)64 * D; vg0 += 64; vg1 += 64;
  __syncthreads();

  int cur = 0;
  for (int kt = 0; kt < nkt; ++kt) {
    if (kt + 1 < nkt) {                            // prefetch next tile
      bf16* Kn = &Ks[cur ^ 1][0];
      bf16* Vn = &Vt[cur ^ 1][0];
      load_lds16(kg0, &Kn[kl0]);
      load_lds16(kg1, &Kn[kl1]);
      load_lds16(vg0, &Vn[kl0]);
      load_lds16(vg1, &Vn[kl1]);
      kg0 += (size_t)64 * D; kg1 += (size_t)64 * D; vg0 += 64; vg1 += 64;
    }

    const bf16* Kc = &Ks[cur][0];
    const bf16* Vc = &Vt[cur][0];

    // S^T per 16-key subtile: s[sub][r] = S[key=sub*16+quad*4+r][q=l16]
    f32x4 s[4];
    #pragma unroll
    for (int sub = 0; sub < 4; ++sub) {
      bf16x8 k0 = *(const bf16x8*)&Kc[(sub * 16 + l16) * 64 + s0];
      bf16x8 k1 = *(const bf16x8*)&Kc[(sub * 16 + l16) * 64 + s1];
      f32x4 a = {};
      a = mfma(k0, qf0, a);
      a = mfma(k1, qf1, a);
      s[sub] = a;
    }

    if (kt == qt) { // diagonal causal mask (tile-local)
      const int qloc = wave * 16 + l16;
      #pragma unroll
      for (int sub = 0; sub < 4; ++sub)
        #pragma unroll
        for (int r = 0; r < 4; ++r)
          if (sub * 16 + quad * 4 + r > qloc) s[sub][r] = -1e30f;
    }

    // tile max via max3 triples, then cross-quad reduce (state for q = l16)
    const float t0 = max3f(s[0][0], s[0][1], s[0][2]);
    const float t1 = max3f(s[0][3], s[1][0], s[1][1]);
    const float t2 = max3f(s[1][2], s[1][3], s[2][0]);
    const float t3 = max3f(s[2][1], s[2][2], s[2][3]);
    const float t4 = max3f(s[3][0], s[3][1], s[3][2]);
    float mx = fmaxf(max3f(t0, t1, t2), max3f(t3, t4, s[3][3]));
    mx = fmaxf(mx, __shfl_xor(mx, 16, 64));
    mx = fmaxf(mx, __shfl_xor(mx, 32, 64));

    // defer-max: rescale only when max grows by more than 8 (log2 domain)
    if (!__all(mx <= m_run + 8.f)) {
      const float mn = fmaxf(m_run, mx);
      const float alpha = __builtin_amdgcn_exp2f(m_run - mn);
      m_run = mn;
      #pragma unroll
      for (int r = 0; r < 4; ++r) {
        const float ar = __shfl(alpha, quad * 4 + r, 64);
        o_sum[r] *= ar;
        #pragma unroll
        for (int db = 0; db < 4; ++db) o_acc[db][r] *= ar;
      }
    }

    // pack P in-register (A-frag slot (quad,j): key (j<4?quad*4+j:16+quad*4+j-4)+32c)
    bf16x8 fr0, fr1;
    #pragma unroll
    for (int r = 0; r < 4; ++r) {
      fr0[r]     = (bf16)__builtin_amdgcn_exp2f(s[0][r] - m_run);
      fr0[4 + r] = (bf16)__builtin_amdgcn_exp2f(s[1][r] - m_run);
      fr1[r]     = (bf16)__builtin_amdgcn_exp2f(s[2][r] - m_run);
      fr1[4 + r] = (bf16)__builtin_amdgcn_exp2f(s[3][r] - m_run);
    }

    // O += P @ V ; row-sum += P @ 1 (denominator on the MFMA pipe)
    o_sum = mfma(fr0, ones, o_sum);
    o_sum = mfma(fr1, ones, o_sum);
    #pragma unroll
    for (int db = 0; db < 4; ++db) {
      bf16x8 v0 = *(const bf16x8*)&Vc[(db * 16 + l16) * 64 + s0];
      bf16x8 v1 = *(const bf16x8*)&Vc[(db * 16 + l16) * 64 + s1];
      o_acc[db] = mfma(fr0, v0, o_acc[db]);
      o_acc[db] = mfma(fr1, v1, o_acc[db]);
    }

    // single barrier: drains prefetch AND protects buf reuse
    __syncthreads();
    cur ^= 1;
  }

  #pragma unroll
  for (int r = 0; r < 4; ++r) {
    const float inv = 1.f / o_sum[r];   // shuffle-free: o_sum row == o_acc row
    const int row = qt * 64 + wave * 16 + quad * 4 + r;
    #pragma unroll
    for (int db = 0; db < 4; ++db)
      Qb[(size_t)row * D + db * 16 + l16] = (bf16)(o_acc[db][r] * inv);
  }
}

extern "C" void kernel_launch(void* const* d_in, const int* in_sizes, int n_in,
                              void* d_out, int out_size, void* d_ws, size_t ws_size,
                              hipStream_t stream) {
  const void* x  = d_in[0];
  const void* Wq = d_in[1];
  const void* bq = d_in[2];
  const void* Wk = d_in[3];
  const void* bk = d_in[4];
  const void* Wv = d_in[5];
  const void* bv = d_in[6];
  const void* Wo = d_in[7];
  const void* bo = d_in[8];
  // d_in[9] = causal mask, analytic

  int* flag = (int*)d_ws;
  char* p = (char*)d_ws + 4096;
  bf16* xc  = (bf16*)p;                 p += (size_t)BL * D * 2;
  bf16* WqT = (bf16*)p;                 p += (size_t)D * D * 2; // WqT/WkT/WvT/WoT
  bf16* WkT = (bf16*)p;                 p += (size_t)D * D * 2; // contiguous =
  bf16* WvT = (bf16*)p;                 p += (size_t)D * D * 2; // stacked [4096][1024]
  bf16* WoT = (bf16*)p;                 p += (size_t)D * D * 2;
  bf16* Qb  = (bf16*)p;                 p += (size_t)BL * D * 2; // O aliases Q
  bf16* Kb  = (bf16*)p;                 p += (size_t)BL * D * 2;
  bf16* VTb = (bf16*)p;                 // V^T written directly by qkv_gemm

  sniff_k<<<1, 256, 0, stream>>>((const unsigned short*)x, flag);

  prep_k<<<dim3(32, 32, 5), 256, 0, stream>>>(Wq, Wk, Wv, Wo, WqT, x, xc, flag, BL * D);

  qkv_gemm_k<<<dim3(GM / 256, 3072 / 128), 512, 0, stream>>>(
      xc, WqT, bq, bk, bv, Qb, Kb, VTb, flag);

  attn_k<<<dim3((L / 64) * B * H), 256, 0, stream>>>(Qb, Kb, VTb);

  gemm_bt_k<<<dim3(GM / 256, D / 128), 512, 0, stream>>>(Qb, WoT, bo, d_out, flag);
}

// Round 12
// 274.103 us; speedup vs baseline: 1.0016x; 1.0016x over previous
//
#include <hip/hip_runtime.h>
#include <hip/hip_bf16.h>

// MHA: B=4 L=2048 D=1024 H=16 DH=64, causal. Inputs f32 (sniffed; dtype-proof).
// Round 19: qkv_gemm counted-vmcnt dbuf (T4 mechanism, simplified schedule).
//  R18 counters: qkv = 67us, MfmaUtil 30%, VALU 25%, HBM 22% -- the documented
//  m97-structure ceiling (__syncthreads vmcnt(0) drain exposes staging).
//  New K-loop: raw s_barrier (no drain) + counted s_waitcnt vmcnt(6), loads
//  for tile t+2 stay in flight across both barriers. Schedule proof:
//    barrier#1 after compute -> no wave reads buf[cur] when STAGE overwrites;
//    own vmcnt(6) -> own t+1 loads landed; barrier#2 -> ALL waves' t+1 landed
//    before any wave reads buf[cur^1]. Tail: vmcnt(0) when no stage issued.
//  Geometry = R18-verified (BM=256xBN=128, 512thr, same swizzle/epilogues);
//  LDS 96KB dbuf -> 1 block/CU; grid 768 = 3/CU balanced.
//  gemm_bt reverted to known-good 128^2/256thr. attn = R14-exact (65.9 best;
//  setprio removed per R17 A/B). prep/sniff unchanged.

typedef __bf16 bf16;
typedef __bf16 bf16x4 __attribute__((ext_vector_type(4)));
typedef __bf16 bf16x8 __attribute__((ext_vector_type(8)));
typedef float f32x4 __attribute__((ext_vector_type(4)));

#define DEV static __device__ __forceinline__

constexpr int B = 4, L = 2048, D = 1024, H = 16, DH = 64;
constexpr int BL = B * L;                      // 8192
constexpr int GM = 8192, GK = 1024;
constexpr int BKg = 64;                        // GEMM K-tile

typedef __attribute__((address_space(1))) const void* gptr1;
typedef __attribute__((address_space(3))) void* lptr3;

DEV void load_lds16(const bf16* g, bf16* l) {
  __builtin_amdgcn_global_load_lds((gptr1)g, (lptr3)l, 16, 0, 0);
}

DEV f32x4 mfma(bf16x8 a, bf16x8 b, f32x4 c) {
  return __builtin_amdgcn_mfma_f32_16x16x32_bf16(a, b, c, 0, 0, 0);
}

DEV float scrub(float v) { return (v == v) ? v : 0.f; }
DEV float max3f(float a, float b, float c) { return fmaxf(fmaxf(a, b), c); }

// ---------- dtype sniff (flag=1: bf16 storage, 0: f32) ----------
__global__ void sniff_k(const unsigned short* __restrict__ xr, int* flag) {
  __shared__ int cnt;
  if (threadIdx.x == 0) cnt = 0;
  __syncthreads();
  int local = 0;
  for (int i = threadIdx.x; i < 4096; i += 256) {
    const unsigned short u = xr[2 * i];
    const int e = (u >> 7) & 0xFF;
    if (e >= 0x70 && e <= 0x85) local++;
  }
  atomicAdd(&cnt, local);
  __syncthreads();
  if (threadIdx.x == 0) *flag = (cnt > 2048) ? 1 : 0;
}

// ---------- merged prep: z=0..3 weight transpose, z=4 x canonicalize ----------
__global__ __launch_bounds__(256) void prep_k(const void* __restrict__ W0,
                                              const void* __restrict__ W1,
                                              const void* __restrict__ W2,
                                              const void* __restrict__ W3,
                                              bf16* __restrict__ dstBase,
                                              const void* __restrict__ x,
                                              bf16* __restrict__ xc,
                                              const int* __restrict__ flag, int n) {
  __shared__ bf16 t[32][33];
  const bool isbf = (*flag != 0);
  const int z = blockIdx.z;
  if (z < 4) {
    const void* src = (z == 0) ? W0 : (z == 1) ? W1 : (z == 2) ? W2 : W3;
    bf16* dst = dstBase + (size_t)z * D * D;
    const int bx = blockIdx.x * 32, by = blockIdx.y * 32;
    const int tx = threadIdx.x & 31, ty = threadIdx.x >> 5;
    for (int i = ty; i < 32; i += 8) {
      const size_t off = (size_t)(by + i) * D + bx + tx;
      const float v = isbf ? (float)((const bf16*)src)[off] : ((const float*)src)[off];
      t[i][tx] = (bf16)scrub(v);
    }
    __syncthreads();
    for (int i = ty; i < 32; i += 8)
      dst[(size_t)(bx + i) * D + by + tx] = t[tx][i];
  } else {
    const int bid = blockIdx.y * 32 + blockIdx.x;       // 0..1023
    const int stride = 1024 * 256 * 8;
    for (int idx = (bid * 256 + (int)threadIdx.x) * 8; idx < n; idx += stride) {
      bf16x8 o;
      if (isbf) {
        bf16x8 v = *(const bf16x8*)((const bf16*)x + idx);
        #pragma unroll
        for (int j = 0; j < 8; ++j) o[j] = (bf16)scrub((float)v[j]);
      } else {
        const float* s = (const float*)x + idx;
        #pragma unroll
        for (int j = 0; j < 8; ++j) o[j] = (bf16)scrub(s[j]);
      }
      *(bf16x8*)&xc[idx] = o;
    }
  }
}

// ---------- fused QKV GEMM: [Q|K|V] = x @ [WqT|WkT|WvT]^T + b ----------
// 256x128 tile, 512 threads, 8 waves (4 m-rows x 2 n-cols of 64x64 each).
// Counted-vmcnt double-buffered K-loop (raw barriers, loads in flight 2 deep).
// Q epilogue folds 0.125*log2(e); V epilogue writes VT[bh][d][pos] directly
// (position permutation pos = 4*hi16 + 8*q4 + r within each 32-key group).
__global__ __launch_bounds__(512) void qkv_gemm_k(const bf16* __restrict__ A,
                                                  const bf16* __restrict__ Bt,
                                                  const void* __restrict__ bq,
                                                  const void* __restrict__ bk,
                                                  const void* __restrict__ bv,
                                                  bf16* __restrict__ Q,
                                                  bf16* __restrict__ Kk,
                                                  bf16* __restrict__ VT,
                                                  const int* __restrict__ flag) {
  __shared__ __align__(16) bf16 As[2][256 * BKg];
  __shared__ __align__(16) bf16 Bs[2][128 * BKg];
  const bool isbf = (*flag != 0);
  const int m0 = blockIdx.x * 256, n0 = blockIdx.y * 128;
  const int buf = n0 >> 10, nloc = n0 & 1023;
  const void* bias = (buf == 0) ? bq : (buf == 1) ? bk : bv;
  const float scale = (buf == 0) ? 0.18033688011111f : 1.0f; // 0.125*log2(e)

  const int tid = threadIdx.x, wave = tid >> 6, lane = tid & 63;
  const int wr = wave >> 1, wc = wave & 1;   // 4 m-rows x 2 n-cols
  const int quad = lane >> 4, l16 = lane & 15;
  const int srow = lane >> 3;
  const int scol = ((lane ^ srow) & 7) * 8;
  const int l7 = l16 & 7;
  const int s0 = ((quad ^ l7) * 8);
  const int s1 = s0 ^ 32;

  f32x4 acc[4][4] = {};

  // per-thread loads per K-tile: 4 (A) + 2 (B) = 6  -> vmcnt counts below
  #define STAGE_QKV(sl, k0q)                                                       \
    do {                                                                           \
      _Pragma("unroll")                                                            \
      for (int c = wave; c < 32; c += 8)                                           \
        load_lds16(A  + (size_t)(m0 + c * 8 + srow) * GK + (k0q) + scol,           \
                   &As[sl][c * 512]);                                              \
      _Pragma("unroll")                                                            \
      for (int c = wave; c < 16; c += 8)                                           \
        load_lds16(Bt + (size_t)(n0 + c * 8 + srow) * GK + (k0q) + scol,           \
                   &Bs[sl][c * 512]);                                              \
    } while (0)

  // prologue: tiles 0,1 staged; wait own tile-0 loads; sync
  STAGE_QKV(0, 0);
  STAGE_QKV(1, BKg);
  asm volatile("s_waitcnt vmcnt(6)" ::: "memory");
  __builtin_amdgcn_s_barrier();
  __builtin_amdgcn_sched_barrier(0);

  const int nt = GK / BKg;                   // 16
  for (int t = 0; t < nt; ++t) {
    const int cur = t & 1;
    const bf16* Asc = &As[cur][0];
    const bf16* Bsc = &Bs[cur][0];
    #pragma unroll
    for (int kk = 0; kk < BKg; kk += 32) {
      const int sk = kk ? s1 : s0;
      bf16x8 af[4], bfr[4];
      #pragma unroll
      for (int i = 0; i < 4; ++i)
        af[i] = *(const bf16x8*)&Asc[(wr * 64 + i * 16 + l16) * BKg + sk];
      #pragma unroll
      for (int i = 0; i < 4; ++i)
        bfr[i] = *(const bf16x8*)&Bsc[(wc * 64 + i * 16 + l16) * BKg + sk];
      #pragma unroll
      for (int mi = 0; mi < 4; ++mi)
        #pragma unroll
        for (int ni = 0; ni < 4; ++ni)
          acc[mi][ni] = mfma(af[mi], bfr[ni], acc[mi][ni]);
    }

    // all waves finished READING buf[cur] before any wave overwrites it
    __builtin_amdgcn_s_barrier();
    __builtin_amdgcn_sched_barrier(0);

    if (t + 2 < nt) {
      STAGE_QKV(cur, (t + 2) * BKg);                   // 6 more loads in flight
      asm volatile("s_waitcnt vmcnt(6)" ::: "memory"); // own t+1 loads landed
    } else {
      asm volatile("s_waitcnt vmcnt(0)" ::: "memory"); // tail: drain everything
    }

    // all waves' t+1 loads landed before any wave reads buf[cur^1]
    __builtin_amdgcn_s_barrier();
    __builtin_amdgcn_sched_barrier(0);
  }
  #undef STAGE_QKV

  if (buf < 2) {
    bf16* Cb = (buf == 0) ? Q : Kk;
    #pragma unroll
    for (int ni = 0; ni < 4; ++ni) {
      const int col = nloc + wc * 64 + ni * 16 + l16;
      const float bv2 = isbf ? (float)((const bf16*)bias)[col] : ((const float*)bias)[col];
      #pragma unroll
      for (int mi = 0; mi < 4; ++mi)
        #pragma unroll
        for (int r = 0; r < 4; ++r) {
          const int row = m0 + wr * 64 + mi * 16 + quad * 4 + r;
          Cb[(size_t)row * D + col] = (bf16)((acc[mi][ni][r] + bv2) * scale);
        }
    }
  } else {
    // V -> VT[bh][d][pos], position-permuted, bf16x4 per acc column
    #pragma unroll
    for (int ni = 0; ni < 4; ++ni) {
      const int col = nloc + wc * 64 + ni * 16 + l16;   // feature c in [0,1024)
      const int h = col >> 6, d = col & 63;
      const float bv2 = isbf ? (float)((const bf16*)bias)[col] : ((const float*)bias)[col];
      #pragma unroll
      for (int mi = 0; mi < 4; ++mi) {
        const int row = m0 + wr * 64 + mi * 16 + quad * 4;  // token base, 4-aligned
        const int bb = row >> 11, l = row & 2047;
        const int pos = (l & ~31) + 4 * ((l >> 4) & 1) + 8 * ((l >> 2) & 3);
        bf16x4 pk;
        #pragma unroll
        for (int r = 0; r < 4; ++r) pk[r] = (bf16)(acc[mi][ni][r] + bv2);
        *(bf16x4*)&VT[((size_t)(bb * 16 + h) * 64 + d) * L + pos] = pk;
      }
    }
  }
}

// ---------- final GEMM: out = attnO @ WoT^T + bo (dtype per flag) ----------
// Known-good 128x128 tile, 256 threads (R13/R17 structure).
__global__ __launch_bounds__(256) void gemm_bt_k(const bf16* __restrict__ A,
                                                 const bf16* __restrict__ Bt,
                                                 const void* __restrict__ bias,
                                                 void* __restrict__ C,
                                                 const int* __restrict__ flag) {
  __shared__ __align__(16) bf16 As[128 * BKg];
  __shared__ __align__(16) bf16 Bs[128 * BKg];
  const bool isbf = (*flag != 0);
  const int m0 = blockIdx.x * 128, n0 = blockIdx.y * 128;
  const int tid = threadIdx.x, wave = tid >> 6, lane = tid & 63;
  const int wr = wave >> 1, wc = wave & 1;
  const int quad = lane >> 4, l16 = lane & 15;
  const int srow = lane >> 3;
  const int scol = ((lane ^ srow) & 7) * 8;
  const int l7 = l16 & 7;
  const int s0 = ((quad ^ l7) * 8);
  const int s1 = s0 ^ 32;

  f32x4 acc[4][4] = {};

  for (int k0 = 0; k0 < GK; k0 += BKg) {
    for (int c = wave; c < 16; c += 4) {
      load_lds16(A  + (size_t)(m0 + c * 8 + srow) * GK + k0 + scol, &As[c * 512]);
      load_lds16(Bt + (size_t)(n0 + c * 8 + srow) * GK + k0 + scol, &Bs[c * 512]);
    }
    __syncthreads();
    #pragma unroll
    for (int kk = 0; kk < BKg; kk += 32) {
      const int sk = kk ? s1 : s0;
      bf16x8 af[4], bfr[4];
      #pragma unroll
      for (int i = 0; i < 4; ++i)
        af[i] = *(const bf16x8*)&As[(wr * 64 + i * 16 + l16) * BKg + sk];
      #pragma unroll
      for (int i = 0; i < 4; ++i)
        bfr[i] = *(const bf16x8*)&Bs[(wc * 64 + i * 16 + l16) * BKg + sk];
      #pragma unroll
      for (int mi = 0; mi < 4; ++mi)
        #pragma unroll
        for (int ni = 0; ni < 4; ++ni)
          acc[mi][ni] = mfma(af[mi], bfr[ni], acc[mi][ni]);
    }
    __syncthreads();
  }

  bf16* Cb = (bf16*)C;
  float* Cf = (float*)C;
  #pragma unroll
  for (int ni = 0; ni < 4; ++ni) {
    const int col = n0 + wc * 64 + ni * 16 + l16;
    const float bv = isbf ? (float)((const bf16*)bias)[col] : ((const float*)bias)[col];
    #pragma unroll
    for (int mi = 0; mi < 4; ++mi)
      #pragma unroll
      for (int r = 0; r < 4; ++r) {
        const int row = m0 + wr * 64 + mi * 16 + quad * 4 + r;
        const float v = acc[mi][ni][r] + bv;
        if (isbf) Cb[(size_t)row * D + col] = (bf16)v;
        else      Cf[(size_t)row * D + col] = v;
      }
  }
}

// ---------- fused causal flash attention v8.2 (R14-exact, no setprio) ----------
// QBLK=64: 4 waves x 16 q-rows, 64-key tiles. In-register P on 16x16x32,
// position-permuted V^T, dbuf + prefetch + 1 barrier/tile, exp2 domain,
// defer-max THR=8, MFMA-ones o_sum, running staging pointers.
__global__ __launch_bounds__(256) void attn_k(bf16* QO,
                                              const bf16* __restrict__ K,
                                              const bf16* __restrict__ VT) {
  __shared__ __align__(16) bf16 Ks[2][64 * 64];    // swizzled [key][d], dbuf
  __shared__ __align__(16) bf16 Vt[2][64 * 64];    // swizzled [d][pos], dbuf

  const int bx = blockIdx.x;
  const int qt = (L / 64 - 1) - (bx >> 6);         // longest blocks first
  const int bh = bx & 63;
  const int b = bh >> 4, h = bh & 15;
  const int tid = threadIdx.x, wave = tid >> 6, lane = tid & 63;
  const int quad = lane >> 4, l16 = lane & 15;
  const int srow = lane >> 3;
  const int scol = ((lane ^ srow) & 7) * 8;
  const int l7 = l16 & 7;
  const int s0 = ((quad ^ l7) * 8);
  const int s1 = s0 ^ 32;

  bf16* Qb = QO + (size_t)b * L * D + h * DH;
  const bf16* Kb = K + (size_t)b * L * D + h * DH;
  const bf16* VTg = VT + (size_t)bh * DH * L;

  // Q B-frags (scale 0.125*log2e pre-folded by QKV GEMM)
  const int qrow = qt * 64 + wave * 16 + l16;
  const bf16x8 qf0 = *(const bf16x8*)(Qb + (size_t)qrow * D + quad * 8);
  const bf16x8 qf1 = *(const bf16x8*)(Qb + (size_t)qrow * D + 32 + quad * 8);

  bf16x8 ones;
  #pragma unroll
  for (int j = 0; j < 8; ++j) ones[j] = (bf16)1.0f;

  float m_run = -INFINITY;                // log2-domain max for q = l16
  f32x4 o_acc[4] = {};                    // C row=quad*4+r -> q, col=l16 -> d
  f32x4 o_sum = {};                       // MFMA row-sum, same layout

  const int nkt = qt + 1;

  // staging pointers (this wave's two chunks), advanced per tile
  const bf16* kg0 = Kb + (size_t)(wave * 8 + srow) * D + scol;
  const bf16* kg1 = kg0 + (size_t)32 * D;
  const bf16* vg0 = VTg + (size_t)(wave * 8 + srow) * L + scol;
  const bf16* vg1 = vg0 + (size_t)32 * L;
  const int kl0 = wave * 512, kl1 = kl0 + 2048;    // LDS chunk offsets

  // prologue: stage tile 0 into buf 0
  load_lds16(kg0, &Ks[0][kl0]);
  load_lds16(kg1, &Ks[0][kl1]);
  load_lds16(vg0, &Vt[0][kl0]);
  load_lds16(vg1, &Vt[0][kl1]);
  kg0 += (size_t)64 * D; kg1 += (size_t)64 * D; vg0 += 64; vg1 += 64;
  __syncthreads();

  int cur = 0;
  for (int kt = 0; kt < nkt; ++kt) {
    if (kt + 1 < nkt) {                            // prefetch next tile
      bf16* Kn = &Ks[cur ^ 1][0];
      bf16* Vn = &Vt[cur ^ 1][0];
      load_lds16(kg0, &Kn[kl0]);
      load_lds16(kg1, &Kn[kl1]);
      load_lds16(vg0, &Vn[kl0]);
      load_lds16(vg1, &Vn[kl1]);
      kg0 += (size_t)64 * D; kg1 += (size_t)64 * D; vg0 += 64; vg1 += 64;
    }

    const bf16* Kc = &Ks[cur][0];
    const bf16* Vc = &Vt[cur][0];

    // S^T per 16-key subtile: s[sub][r] = S[key=sub*16+quad*4+r][q=l16]
    f32x4 s[4];
    #pragma unroll
    for (int sub = 0; sub < 4; ++sub) {
      bf16x8 k0 = *(const bf16x8*)&Kc[(sub * 16 + l16) * 64 + s0];
      bf16x8 k1 = *(const bf16x8*)&Kc[(sub * 16 + l16) * 64 + s1];
      f32x4 a = {};
      a = mfma(k0, qf0, a);
      a = mfma(k1, qf1, a);
      s[sub] = a;
    }

    if (kt == qt) { // diagonal causal mask (tile-local)
      const int qloc = wave * 16 + l16;
      #pragma unroll
      for (int sub = 0; sub < 4; ++sub)
        #pragma unroll
        for (int r = 0; r < 4; ++r)
          if (sub * 16 + quad * 4 + r > qloc) s[sub][r] = -1e30f;
    }

    // tile max via max3 triples, then cross-quad reduce (state for q = l16)
    const float t0 = max3f(s[0][0], s[0][1], s[0][2]);
    const float t1 = max3f(s[0][3], s[1][0], s[1][1]);
    const float t2 = max3f(s[1][2], s[1][3], s[2][0]);
    const float t3 = max3f(s[2][1], s[2][2], s[2][3]);
    const float t4 = max3f(s[3][0], s[3][1], s[3][2]);
    float mx = fmaxf(max3f(t0, t1, t2), max3f(t3, t4, s[3][3]));
    mx = fmaxf(mx, __shfl_xor(mx, 16, 64));
    mx = fmaxf(mx, __shfl_xor(mx, 32, 64));

    // defer-max: rescale only when max grows by more than 8 (log2 domain)
    if (!__all(mx <= m_run + 8.f)) {
      const float mn = fmaxf(m_run, mx);
      const float alpha = __builtin_amdgcn_exp2f(m_run - mn);
      m_run = mn;
      #pragma unroll
      for (int r = 0; r < 4; ++r) {
        const float ar = __shfl(alpha, quad * 4 + r, 64);
        o_sum[r] *= ar;
        #pragma unroll
        for (int db = 0; db < 4; ++db) o_acc[db][r] *= ar;
      }
    }

    // pack P in-register (A-frag slot (quad,j): key (j<4?quad*4+j:16+quad*4+j-4)+32c)
    bf16x8 fr0, fr1;
    #pragma unroll
    for (int r = 0; r < 4; ++r) {
      fr0[r]     = (bf16)__builtin_amdgcn_exp2f(s[0][r] - m_run);
      fr0[4 + r] = (bf16)__builtin_amdgcn_exp2f(s[1][r] - m_run);
      fr1[r]     = (bf16)__builtin_amdgcn_exp2f(s[2][r] - m_run);
      fr1[4 + r] = (bf16)__builtin_amdgcn_exp2f(s[3][r] - m_run);
    }

    // O += P @ V ; row-sum += P @ 1 (denominator on the MFMA pipe)
    o_sum = mfma(fr0, ones, o_sum);
    o_sum = mfma(fr1, ones, o_sum);
    #pragma unroll
    for (int db = 0; db < 4; ++db) {
      bf16x8 v0 = *(const bf16x8*)&Vc[(db * 16 + l16) * 64 + s0];
      bf16x8 v1 = *(const bf16x8*)&Vc[(db * 16 + l16) * 64 + s1];
      o_acc[db] = mfma(fr0, v0, o_acc[db]);
      o_acc[db] = mfma(fr1, v1, o_acc[db]);
    }

    // single barrier: drains prefetch AND protects buf reuse
    __syncthreads();
    cur ^= 1;
  }

  #pragma unroll
  for (int r = 0; r < 4; ++r) {
    const float inv = 1.f / o_sum[r];   // shuffle-free: o_sum row == o_acc row
    const int row = qt * 64 + wave * 16 + quad * 4 + r;
    #pragma unroll
    for (int db = 0; db < 4; ++db)
      Qb[(size_t)row * D + db * 16 + l16] = (bf16)(o_acc[db][r] * inv);
  }
}

extern "C" void kernel_launch(void* const* d_in, const int* in_sizes, int n_in,
                              void* d_out, int out_size, void* d_ws, size_t ws_size,
                              hipStream_t stream) {
  const void* x  = d_in[0];
  const void* Wq = d_in[1];
  const void* bq = d_in[2];
  const void* Wk = d_in[3];
  const void* bk = d_in[4];
  const void* Wv = d_in[5];
  const void* bv = d_in[6];
  const void* Wo = d_in[7];
  const void* bo = d_in[8];
  // d_in[9] = causal mask, analytic

  int* flag = (int*)d_ws;
  char* p = (char*)d_ws + 4096;
  bf16* xc  = (bf16*)p;                 p += (size_t)BL * D * 2;
  bf16* WqT = (bf16*)p;                 p += (size_t)D * D * 2; // WqT/WkT/WvT/WoT
  bf16* WkT = (bf16*)p;                 p += (size_t)D * D * 2; // contiguous =
  bf16* WvT = (bf16*)p;                 p += (size_t)D * D * 2; // stacked [4096][1024]
  bf16* WoT = (bf16*)p;                 p += (size_t)D * D * 2;
  bf16* Qb  = (bf16*)p;                 p += (size_t)BL * D * 2; // O aliases Q
  bf16* Kb  = (bf16*)p;                 p += (size_t)BL * D * 2;
  bf16* VTb = (bf16*)p;                 // V^T written directly by qkv_gemm

  sniff_k<<<1, 256, 0, stream>>>((const unsigned short*)x, flag);

  prep_k<<<dim3(32, 32, 5), 256, 0, stream>>>(Wq, Wk, Wv, Wo, WqT, x, xc, flag, BL * D);

  qkv_gemm_k<<<dim3(GM / 256, 3072 / 128), 512, 0, stream>>>(
      xc, WqT, bq, bk, bv, Qb, Kb, VTb, flag);

  attn_k<<<dim3((L / 64) * B * H), 256, 0, stream>>>(Qb, Kb, VTb);

  gemm_bt_k<<<dim3(GM / 128, D / 128), 256, 0, stream>>>(Qb, WoT, bo, d_out, flag);
}

// Round 13
// 264.083 us; speedup vs baseline: 1.0396x; 1.0379x over previous
//
#include <hip/hip_runtime.h>
#include <hip/hip_bf16.h>

// MHA: B=4 L=2048 D=1024 H=16 DH=64, causal. Inputs f32 (sniffed; dtype-proof).
// Round 20: CONSOLIDATION of measured-best components (no new mechanisms).
//  Ledger: attn QBLK=64 no-setprio = 65.9us (QBLK=128: -4.3; setprio: -4.5);
//  qkv 128^2/256thr single-buffer = ~67us (BM=256: neutral; XCD swizzle: -;
//  counted-vmcnt dbuf: -9 -- R19 confirmed guide's "T4 null at 2-phase" gate);
//  gemm_bt 128^2 = ~22us; prep merged + 4-wave sniff: neutral-positive.
//  This file = R17 exactly, with attn's setprio pairs removed (R14-exact attn).
// attn core: in-register P on 16x16x32, no P-LDS, dbuf + prefetch + 1
// barrier/tile, exp2 domain, defer-max THR=8, MFMA-ones o_sum, position-
// permuted V^T from qkv epilogue, running staging pointers.
// Remaining documented headroom: 8-phase 256^2 schedule for qkv (T3+T4 gate) --
// high-risk sync-structure rewrite, not attempted in this one-shot loop.

typedef __bf16 bf16;
typedef __bf16 bf16x4 __attribute__((ext_vector_type(4)));
typedef __bf16 bf16x8 __attribute__((ext_vector_type(8)));
typedef float f32x4 __attribute__((ext_vector_type(4)));

#define DEV static __device__ __forceinline__

constexpr int B = 4, L = 2048, D = 1024, H = 16, DH = 64;
constexpr int BL = B * L;                      // 8192
constexpr int GM = 8192, GK = 1024;
constexpr int BKg = 64;                        // GEMM K-tile

typedef __attribute__((address_space(1))) const void* gptr1;
typedef __attribute__((address_space(3))) void* lptr3;

DEV void load_lds16(const bf16* g, bf16* l) {
  __builtin_amdgcn_global_load_lds((gptr1)g, (lptr3)l, 16, 0, 0);
}

DEV f32x4 mfma(bf16x8 a, bf16x8 b, f32x4 c) {
  return __builtin_amdgcn_mfma_f32_16x16x32_bf16(a, b, c, 0, 0, 0);
}

DEV float scrub(float v) { return (v == v) ? v : 0.f; }
DEV float max3f(float a, float b, float c) { return fmaxf(fmaxf(a, b), c); }

// ---------- dtype sniff (flag=1: bf16 storage, 0: f32) ----------
__global__ void sniff_k(const unsigned short* __restrict__ xr, int* flag) {
  __shared__ int cnt;
  if (threadIdx.x == 0) cnt = 0;
  __syncthreads();
  int local = 0;
  for (int i = threadIdx.x; i < 4096; i += 256) {
    const unsigned short u = xr[2 * i];
    const int e = (u >> 7) & 0xFF;
    if (e >= 0x70 && e <= 0x85) local++;
  }
  atomicAdd(&cnt, local);
  __syncthreads();
  if (threadIdx.x == 0) *flag = (cnt > 2048) ? 1 : 0;
}

// ---------- merged prep: z=0..3 weight transpose, z=4 x canonicalize ----------
__global__ __launch_bounds__(256) void prep_k(const void* __restrict__ W0,
                                              const void* __restrict__ W1,
                                              const void* __restrict__ W2,
                                              const void* __restrict__ W3,
                                              bf16* __restrict__ dstBase,
                                              const void* __restrict__ x,
                                              bf16* __restrict__ xc,
                                              const int* __restrict__ flag, int n) {
  __shared__ bf16 t[32][33];
  const bool isbf = (*flag != 0);
  const int z = blockIdx.z;
  if (z < 4) {
    const void* src = (z == 0) ? W0 : (z == 1) ? W1 : (z == 2) ? W2 : W3;
    bf16* dst = dstBase + (size_t)z * D * D;
    const int bx = blockIdx.x * 32, by = blockIdx.y * 32;
    const int tx = threadIdx.x & 31, ty = threadIdx.x >> 5;
    for (int i = ty; i < 32; i += 8) {
      const size_t off = (size_t)(by + i) * D + bx + tx;
      const float v = isbf ? (float)((const bf16*)src)[off] : ((const float*)src)[off];
      t[i][tx] = (bf16)scrub(v);
    }
    __syncthreads();
    for (int i = ty; i < 32; i += 8)
      dst[(size_t)(bx + i) * D + by + tx] = t[tx][i];
  } else {
    const int bid = blockIdx.y * 32 + blockIdx.x;       // 0..1023
    const int stride = 1024 * 256 * 8;
    for (int idx = (bid * 256 + (int)threadIdx.x) * 8; idx < n; idx += stride) {
      bf16x8 o;
      if (isbf) {
        bf16x8 v = *(const bf16x8*)((const bf16*)x + idx);
        #pragma unroll
        for (int j = 0; j < 8; ++j) o[j] = (bf16)scrub((float)v[j]);
      } else {
        const float* s = (const float*)x + idx;
        #pragma unroll
        for (int j = 0; j < 8; ++j) o[j] = (bf16)scrub(s[j]);
      }
      *(bf16x8*)&xc[idx] = o;
    }
  }
}

// ---------- fused QKV GEMM: [Q|K|V] = x @ [WqT|WkT|WvT]^T + b ----------
// 128x128 tile, 256 threads (measured-best structure).
// Q epilogue folds 0.125*log2(e); V epilogue writes VT[bh][d][pos] directly
// (position permutation pos = 4*hi16 + 8*q4 + r within each 32-key group).
__global__ __launch_bounds__(256) void qkv_gemm_k(const bf16* __restrict__ A,
                                                  const bf16* __restrict__ Bt,
                                                  const void* __restrict__ bq,
                                                  const void* __restrict__ bk,
                                                  const void* __restrict__ bv,
                                                  bf16* __restrict__ Q,
                                                  bf16* __restrict__ Kk,
                                                  bf16* __restrict__ VT,
                                                  const int* __restrict__ flag) {
  __shared__ __align__(16) bf16 As[128 * BKg];
  __shared__ __align__(16) bf16 Bs[128 * BKg];
  const bool isbf = (*flag != 0);
  const int m0 = blockIdx.x * 128, n0 = blockIdx.y * 128;
  const int buf = n0 >> 10, nloc = n0 & 1023;
  const void* bias = (buf == 0) ? bq : (buf == 1) ? bk : bv;
  const float scale = (buf == 0) ? 0.18033688011111f : 1.0f; // 0.125*log2(e)

  const int tid = threadIdx.x, wave = tid >> 6, lane = tid & 63;
  const int wr = wave >> 1, wc = wave & 1;
  const int quad = lane >> 4, l16 = lane & 15;
  const int srow = lane >> 3;
  const int scol = ((lane ^ srow) & 7) * 8;
  const int l7 = l16 & 7;
  const int s0 = ((quad ^ l7) * 8);
  const int s1 = s0 ^ 32;

  f32x4 acc[4][4] = {};

  for (int k0 = 0; k0 < GK; k0 += BKg) {
    for (int c = wave; c < 16; c += 4) {
      load_lds16(A  + (size_t)(m0 + c * 8 + srow) * GK + k0 + scol, &As[c * 512]);
      load_lds16(Bt + (size_t)(n0 + c * 8 + srow) * GK + k0 + scol, &Bs[c * 512]);
    }
    __syncthreads();
    #pragma unroll
    for (int kk = 0; kk < BKg; kk += 32) {
      const int sk = kk ? s1 : s0;
      bf16x8 af[4], bfr[4];
      #pragma unroll
      for (int i = 0; i < 4; ++i)
        af[i] = *(const bf16x8*)&As[(wr * 64 + i * 16 + l16) * BKg + sk];
      #pragma unroll
      for (int i = 0; i < 4; ++i)
        bfr[i] = *(const bf16x8*)&Bs[(wc * 64 + i * 16 + l16) * BKg + sk];
      #pragma unroll
      for (int mi = 0; mi < 4; ++mi)
        #pragma unroll
        for (int ni = 0; ni < 4; ++ni)
          acc[mi][ni] = mfma(af[mi], bfr[ni], acc[mi][ni]);
    }
    __syncthreads();
  }

  if (buf < 2) {
    bf16* Cb = (buf == 0) ? Q : Kk;
    #pragma unroll
    for (int ni = 0; ni < 4; ++ni) {
      const int col = nloc + wc * 64 + ni * 16 + l16;
      const float bv2 = isbf ? (float)((const bf16*)bias)[col] : ((const float*)bias)[col];
      #pragma unroll
      for (int mi = 0; mi < 4; ++mi)
        #pragma unroll
        for (int r = 0; r < 4; ++r) {
          const int row = m0 + wr * 64 + mi * 16 + quad * 4 + r;
          Cb[(size_t)row * D + col] = (bf16)((acc[mi][ni][r] + bv2) * scale);
        }
    }
  } else {
    // V -> VT[bh][d][pos], position-permuted, bf16x4 per acc column
    #pragma unroll
    for (int ni = 0; ni < 4; ++ni) {
      const int col = nloc + wc * 64 + ni * 16 + l16;   // feature c in [0,1024)
      const int h = col >> 6, d = col & 63;
      const float bv2 = isbf ? (float)((const bf16*)bias)[col] : ((const float*)bias)[col];
      #pragma unroll
      for (int mi = 0; mi < 4; ++mi) {
        const int row = m0 + wr * 64 + mi * 16 + quad * 4;  // token base, 4-aligned
        const int bb = row >> 11, l = row & 2047;
        const int pos = (l & ~31) + 4 * ((l >> 4) & 1) + 8 * ((l >> 2) & 3);
        bf16x4 pk;
        #pragma unroll
        for (int r = 0; r < 4; ++r) pk[r] = (bf16)(acc[mi][ni][r] + bv2);
        *(bf16x4*)&VT[((size_t)(bb * 16 + h) * 64 + d) * L + pos] = pk;
      }
    }
  }
}

// ---------- final GEMM: out = attnO @ WoT^T + bo (dtype per flag) ----------
// 128x128 tile, 256 threads (measured-best structure).
__global__ __launch_bounds__(256) void gemm_bt_k(const bf16* __restrict__ A,
                                                 const bf16* __restrict__ Bt,
                                                 const void* __restrict__ bias,
                                                 void* __restrict__ C,
                                                 const int* __restrict__ flag) {
  __shared__ __align__(16) bf16 As[128 * BKg];
  __shared__ __align__(16) bf16 Bs[128 * BKg];
  const bool isbf = (*flag != 0);
  const int m0 = blockIdx.x * 128, n0 = blockIdx.y * 128;
  const int tid = threadIdx.x, wave = tid >> 6, lane = tid & 63;
  const int wr = wave >> 1, wc = wave & 1;
  const int quad = lane >> 4, l16 = lane & 15;
  const int srow = lane >> 3;
  const int scol = ((lane ^ srow) & 7) * 8;
  const int l7 = l16 & 7;
  const int s0 = ((quad ^ l7) * 8);
  const int s1 = s0 ^ 32;

  f32x4 acc[4][4] = {};

  for (int k0 = 0; k0 < GK; k0 += BKg) {
    for (int c = wave; c < 16; c += 4) {
      load_lds16(A  + (size_t)(m0 + c * 8 + srow) * GK + k0 + scol, &As[c * 512]);
      load_lds16(Bt + (size_t)(n0 + c * 8 + srow) * GK + k0 + scol, &Bs[c * 512]);
    }
    __syncthreads();
    #pragma unroll
    for (int kk = 0; kk < BKg; kk += 32) {
      const int sk = kk ? s1 : s0;
      bf16x8 af[4], bfr[4];
      #pragma unroll
      for (int i = 0; i < 4; ++i)
        af[i] = *(const bf16x8*)&As[(wr * 64 + i * 16 + l16) * BKg + sk];
      #pragma unroll
      for (int i = 0; i < 4; ++i)
        bfr[i] = *(const bf16x8*)&Bs[(wc * 64 + i * 16 + l16) * BKg + sk];
      #pragma unroll
      for (int mi = 0; mi < 4; ++mi)
        #pragma unroll
        for (int ni = 0; ni < 4; ++ni)
          acc[mi][ni] = mfma(af[mi], bfr[ni], acc[mi][ni]);
    }
    __syncthreads();
  }

  bf16* Cb = (bf16*)C;
  float* Cf = (float*)C;
  #pragma unroll
  for (int ni = 0; ni < 4; ++ni) {
    const int col = n0 + wc * 64 + ni * 16 + l16;
    const float bv = isbf ? (float)((const bf16*)bias)[col] : ((const float*)bias)[col];
    #pragma unroll
    for (int mi = 0; mi < 4; ++mi)
      #pragma unroll
      for (int r = 0; r < 4; ++r) {
        const int row = m0 + wr * 64 + mi * 16 + quad * 4 + r;
        const float v = acc[mi][ni][r] + bv;
        if (isbf) Cb[(size_t)row * D + col] = (bf16)v;
        else      Cf[(size_t)row * D + col] = v;
      }
  }
}

// ---------- fused causal flash attention v8.2 (R14-exact, measured best) ----------
// QBLK=64: 4 waves x 16 q-rows, 64-key tiles. In-register P on 16x16x32,
// position-permuted V^T, dbuf + prefetch + 1 barrier/tile, exp2 domain,
// defer-max THR=8, MFMA-ones o_sum, running staging pointers.
__global__ __launch_bounds__(256) void attn_k(bf16* QO,
                                              const bf16* __restrict__ K,
                                              const bf16* __restrict__ VT) {
  __shared__ __align__(16) bf16 Ks[2][64 * 64];    // swizzled [key][d], dbuf
  __shared__ __align__(16) bf16 Vt[2][64 * 64];    // swizzled [d][pos], dbuf

  const int bx = blockIdx.x;
  const int qt = (L / 64 - 1) - (bx >> 6);         // longest blocks first
  const int bh = bx & 63;
  const int b = bh >> 4, h = bh & 15;
  const int tid = threadIdx.x, wave = tid >> 6, lane = tid & 63;
  const int quad = lane >> 4, l16 = lane & 15;
  const int srow = lane >> 3;
  const int scol = ((lane ^ srow) & 7) * 8;
  const int l7 = l16 & 7;
  const int s0 = ((quad ^ l7) * 8);
  const int s1 = s0 ^ 32;

  bf16* Qb = QO + (size_t)b * L * D + h * DH;
  const bf16* Kb = K + (size_t)b * L * D + h * DH;
  const bf16* VTg = VT + (size_t)bh * DH * L;

  // Q B-frags (scale 0.125*log2e pre-folded by QKV GEMM)
  const int qrow = qt * 64 + wave * 16 + l16;
  const bf16x8 qf0 = *(const bf16x8*)(Qb + (size_t)qrow * D + quad * 8);
  const bf16x8 qf1 = *(const bf16x8*)(Qb + (size_t)qrow * D + 32 + quad * 8);

  bf16x8 ones;
  #pragma unroll
  for (int j = 0; j < 8; ++j) ones[j] = (bf16)1.0f;

  float m_run = -INFINITY;                // log2-domain max for q = l16
  f32x4 o_acc[4] = {};                    // C row=quad*4+r -> q, col=l16 -> d
  f32x4 o_sum = {};                       // MFMA row-sum, same layout

  const int nkt = qt + 1;

  // staging pointers (this wave's two chunks), advanced per tile
  const bf16* kg0 = Kb + (size_t)(wave * 8 + srow) * D + scol;
  const bf16* kg1 = kg0 + (size_t)32 * D;
  const bf16* vg0 = VTg + (size_t)(wave * 8 + srow) * L + scol;
  const bf16* vg1 = vg0 + (size_t)32 * L;
  const int kl0 = wave * 512, kl1 = kl0 + 2048;    // LDS chunk offsets

  // prologue: stage tile 0 into buf 0
  load_lds16(kg0, &Ks[0][kl0]);
  load_lds16(kg1, &Ks[0][kl1]);
  load_lds16(vg0, &Vt[0][kl0]);
  load_lds16(vg1, &Vt[0][kl1]);
  kg0 += (size_t)64 * D; kg1 += (size_t)64 * D; vg0 += 64; vg1 += 64;
  __syncthreads();

  int cur = 0;
  for (int kt = 0; kt < nkt; ++kt) {
    if (kt + 1 < nkt) {                            // prefetch next tile
      bf16* Kn = &Ks[cur ^ 1][0];
      bf16* Vn = &Vt[cur ^ 1][0];
      load_lds16(kg0, &Kn[kl0]);
      load_lds16(kg1, &Kn[kl1]);
      load_lds16(vg0, &Vn[kl0]);
      load_lds16(vg1, &Vn[kl1]);
      kg0 += (size_t)64 * D; kg1 += (size_t)64 * D; vg0 += 64; vg1 += 64;
    }

    const bf16* Kc = &Ks[cur][0];
    const bf16* Vc = &Vt[cur][0];

    // S^T per 16-key subtile: s[sub][r] = S[key=sub*16+quad*4+r][q=l16]
    f32x4 s[4];
    #pragma unroll
    for (int sub = 0; sub < 4; ++sub) {
      bf16x8 k0 = *(const bf16x8*)&Kc[(sub * 16 + l16) * 64 + s0];
      bf16x8 k1 = *(const bf16x8*)&Kc[(sub * 16 + l16) * 64 + s1];
      f32x4 a = {};
      a = mfma(k0, qf0, a);
      a = mfma(k1, qf1, a);
      s[sub] = a;
    }

    if (kt == qt) { // diagonal causal mask (tile-local)
      const int qloc = wave * 16 + l16;
      #pragma unroll
      for (int sub = 0; sub < 4; ++sub)
        #pragma unroll
        for (int r = 0; r < 4; ++r)
          if (sub * 16 + quad * 4 + r > qloc) s[sub][r] = -1e30f;
    }

    // tile max via max3 triples, then cross-quad reduce (state for q = l16)
    const float t0 = max3f(s[0][0], s[0][1], s[0][2]);
    const float t1 = max3f(s[0][3], s[1][0], s[1][1]);
    const float t2 = max3f(s[1][2], s[1][3], s[2][0]);
    const float t3 = max3f(s[2][1], s[2][2], s[2][3]);
    const float t4 = max3f(s[3][0], s[3][1], s[3][2]);
    float mx = fmaxf(max3f(t0, t1, t2), max3f(t3, t4, s[3][3]));
    mx = fmaxf(mx, __shfl_xor(mx, 16, 64));
    mx = fmaxf(mx, __shfl_xor(mx, 32, 64));

    // defer-max: rescale only when max grows by more than 8 (log2 domain)
    if (!__all(mx <= m_run + 8.f)) {
      const float mn = fmaxf(m_run, mx);
      const float alpha = __builtin_amdgcn_exp2f(m_run - mn);
      m_run = mn;
      #pragma unroll
      for (int r = 0; r < 4; ++r) {
        const float ar = __shfl(alpha, quad * 4 + r, 64);
        o_sum[r] *= ar;
        #pragma unroll
        for (int db = 0; db < 4; ++db) o_acc[db][r] *= ar;
      }
    }

    // pack P in-register (A-frag slot (quad,j): key (j<4?quad*4+j:16+quad*4+j-4)+32c)
    bf16x8 fr0, fr1;
    #pragma unroll
    for (int r = 0; r < 4; ++r) {
      fr0[r]     = (bf16)__builtin_amdgcn_exp2f(s[0][r] - m_run);
      fr0[4 + r] = (bf16)__builtin_amdgcn_exp2f(s[1][r] - m_run);
      fr1[r]     = (bf16)__builtin_amdgcn_exp2f(s[2][r] - m_run);
      fr1[4 + r] = (bf16)__builtin_amdgcn_exp2f(s[3][r] - m_run);
    }

    // O += P @ V ; row-sum += P @ 1 (denominator on the MFMA pipe)
    o_sum = mfma(fr0, ones, o_sum);
    o_sum = mfma(fr1, ones, o_sum);
    #pragma unroll
    for (int db = 0; db < 4; ++db) {
      bf16x8 v0 = *(const bf16x8*)&Vc[(db * 16 + l16) * 64 + s0];
      bf16x8 v1 = *(const bf16x8*)&Vc[(db * 16 + l16) * 64 + s1];
      o_acc[db] = mfma(fr0, v0, o_acc[db]);
      o_acc[db] = mfma(fr1, v1, o_acc[db]);
    }

    // single barrier: drains prefetch AND protects buf reuse
    __syncthreads();
    cur ^= 1;
  }

  #pragma unroll
  for (int r = 0; r < 4; ++r) {
    const float inv = 1.f / o_sum[r];   // shuffle-free: o_sum row == o_acc row
    const int row = qt * 64 + wave * 16 + quad * 4 + r;
    #pragma unroll
    for (int db = 0; db < 4; ++db)
      Qb[(size_t)row * D + db * 16 + l16] = (bf16)(o_acc[db][r] * inv);
  }
}

extern "C" void kernel_launch(void* const* d_in, const int* in_sizes, int n_in,
                              void* d_out, int out_size, void* d_ws, size_t ws_size,
                              hipStream_t stream) {
  const void* x  = d_in[0];
  const void* Wq = d_in[1];
  const void* bq = d_in[2];
  const void* Wk = d_in[3];
  const void* bk = d_in[4];
  const void* Wv = d_in[5];
  const void* bv = d_in[6];
  const void* Wo = d_in[7];
  const void* bo = d_in[8];
  // d_in[9] = causal mask, analytic

  int* flag = (int*)d_ws;
  char* p = (char*)d_ws + 4096;
  bf16* xc  = (bf16*)p;                 p += (size_t)BL * D * 2;
  bf16* WqT = (bf16*)p;                 p += (size_t)D * D * 2; // WqT/WkT/WvT/WoT
  bf16* WkT = (bf16*)p;                 p += (size_t)D * D * 2; // contiguous =
  bf16* WvT = (bf16*)p;                 p += (size_t)D * D * 2; // stacked [4096][1024]
  bf16* WoT = (bf16*)p;                 p += (size_t)D * D * 2;
  bf16* Qb  = (bf16*)p;                 p += (size_t)BL * D * 2; // O aliases Q
  bf16* Kb  = (bf16*)p;                 p += (size_t)BL * D * 2;
  bf16* VTb = (bf16*)p;                 // V^T written directly by qkv_gemm

  sniff_k<<<1, 256, 0, stream>>>((const unsigned short*)x, flag);

  prep_k<<<dim3(32, 32, 5), 256, 0, stream>>>(Wq, Wk, Wv, Wo, WqT, x, xc, flag, BL * D);

  qkv_gemm_k<<<dim3(GM / 128, 3072 / 128), 256, 0, stream>>>(
      xc, WqT, bq, bk, bv, Qb, Kb, VTb, flag);

  attn_k<<<dim3((L / 64) * B * H), 256, 0, stream>>>(Qb, Kb, VTb);

  gemm_bt_k<<<dim3(GM / 128, D / 128), 256, 0, stream>>>(Qb, WoT, bo, d_out, flag);
}